// Round 1
// baseline (314.287 us; speedup 1.0000x reference)
//
#include <hip/hip_runtime.h>
#include <math.h>

typedef unsigned short u16;
typedef __attribute__((ext_vector_type(8))) short    bf16x8;
typedef __attribute__((ext_vector_type(8))) unsigned short u16x8;
typedef __attribute__((ext_vector_type(4))) float    f32x4;

// Problem constants
#define NB   32        // batch
#define NC   256       // in channels
#define NO   256       // out channels
#define NH   56
#define NW   56
#define NP   3136      // H*W
#define NE   8
#define NID  64
#define HP   58        // padded rows
#define WP   64        // padded row width (aligned)

// Workspace layout (bytes)
#define WMIX_OFF   0                    // u16 [32][9][256][256] = 37,748,736 B
#define XPT_OFF    37748736             // u16 [32][58][64][256] = 60,817,408 B
#define POOL_OFF   98566144             // f32 [32][256]
#define RBUF_OFF   98598912             // f32 [32][8]

__device__ __forceinline__ u16 f2bf(float f) {
    unsigned u = __float_as_uint(f);
    unsigned r = (u + 0x7FFFu + ((u >> 16) & 1u)) >> 16;   // RNE
    return (u16)r;
}

// ---------------------------------------------------------------- kernel 0
__global__ __launch_bounds__(256) void zero_pooled(float* pooled) {
    pooled[blockIdx.x * 256 + threadIdx.x] = 0.0f;
}

// ---------------------------------------------------------------- kernel 1
// Fused: NCHW fp32 -> padded NHWC bf16 transpose  +  channel-sum (pooling)
// xpadT[b][h'][w'][c], h' in [0,58), w' in [0,64); border/pad = 0.
__global__ __launch_bounds__(256) void prep_x(const float* __restrict__ x,
                                              u16* __restrict__ xpadT,
                                              float* __restrict__ pooled) {
    __shared__ u16 tile[64 * 264];            // [wt][c], stride 264 (16B-aligned rows)
    int b  = blockIdx.x / 58;
    int hp = blockIdx.x % 58;
    int t  = threadIdx.x;
    bool interior = (hp >= 1) && (hp <= 56);

    if (interior) {
        int wt = t & 63, ct = t >> 6;         // one wave = one c per iter, lanes = w
        int h = hp - 1;
        const float* xrow = x + (size_t)b * NC * NP + (size_t)h * NW;
        for (int cb = 0; cb < 64; ++cb) {
            int c = cb * 4 + ct;
            float v = (wt < NW) ? xrow[(size_t)c * NP + wt] : 0.0f;
            float s = v;
            #pragma unroll
            for (int off = 32; off; off >>= 1) s += __shfl_xor(s, off, 64);
            if (wt == 0) atomicAdd(&pooled[b * NC + c], s);
            tile[wt * 264 + c] = f2bf(v);
        }
    }
    __syncthreads();

    int c8 = t & 31, wq = t >> 5;             // 32 threads cover 256 c as u16x8
    u16* orow = xpadT + ((size_t)(b * HP + hp)) * WP * NC;
    #pragma unroll
    for (int wi = 0; wi < 8; ++wi) {
        int wp = wq * 8 + wi;
        u16x8 v = {0, 0, 0, 0, 0, 0, 0, 0};
        if (interior && wp >= 1 && wp <= 56)
            v = *(const u16x8*)&tile[(wp - 1) * 264 + c8 * 8];
        *(u16x8*)&orow[wp * NC + c8 * 8] = v;
    }
}

// ---------------------------------------------------------------- kernel 2
// routing: rt = (pooled/3136) @ proj_w^T + proj_b ; sigmoid ; avgpool(8) -> r[32][8]
__global__ __launch_bounds__(64) void routing(const float* __restrict__ pooled,
                                              const float* __restrict__ proj_w,
                                              const float* __restrict__ proj_b,
                                              float* __restrict__ r) {
    __shared__ float ps[256];
    __shared__ float sg[64];
    int b = blockIdx.x, j = threadIdx.x;
    for (int i = j; i < 256; i += 64) ps[i] = pooled[b * NC + i] * (1.0f / 3136.0f);
    __syncthreads();
    float acc = proj_b[j];
    for (int c = 0; c < 256; ++c) acc += ps[c] * proj_w[j * NC + c];
    sg[j] = 1.0f / (1.0f + expf(-acc));
    __syncthreads();
    if (j < NE) {
        float s = 0.0f;
        #pragma unroll
        for (int q = 0; q < 8; ++q) s += sg[j * 8 + q];
        r[b * NE + j] = s * 0.125f;
    }
}

// ---------------------------------------------------------------- kernel 3
// wmix[b][kk][o][c] = bf16( sum_e r[b][e] * expert_w[e][o][c][kk] )
__global__ __launch_bounds__(256) void mix_w(const float* __restrict__ expert_w,
                                             const float* __restrict__ r,
                                             u16* __restrict__ wmix) {
    __shared__ float lr[256];
    int o = blockIdx.x, c = threadIdx.x;
    lr[c] = r[c];                               // 32*8 = 256
    __syncthreads();
    float w[8][9];
    #pragma unroll
    for (int e = 0; e < 8; ++e) {
        const float* p = expert_w + ((size_t)((e * NO + o) * NC + c)) * 9;
        #pragma unroll
        for (int kk = 0; kk < 9; ++kk) w[e][kk] = p[kk];
    }
    for (int b = 0; b < NB; ++b) {
        float acc[9] = {0, 0, 0, 0, 0, 0, 0, 0, 0};
        #pragma unroll
        for (int e = 0; e < 8; ++e) {
            float rv = lr[b * 8 + e];
            #pragma unroll
            for (int kk = 0; kk < 9; ++kk) acc[kk] += rv * w[e][kk];
        }
        #pragma unroll
        for (int kk = 0; kk < 9; ++kk)
            wmix[((size_t)((b * 9 + kk) * NO + o)) * NC + c] = f2bf(acc[kk]);
    }
}

// ---------------------------------------------------------------- kernel 4
// Implicit-GEMM conv: per block b, o-tile 128, p-tile 112 (2 image rows).
// out[o][p] = sum_{kk,c} wmix[b][kk][o][c] * xpadT[b][h+dh+1][w+dw+1][c]
// A LDS: [128 o][64 c] bf16, XOR-swizzled 16B slots (slot g holds col g^(row&7)).
// B LDS: [256 rw][72 c] bf16 padded (rw = (r)*64 + w', 4 padded image rows).
__global__ __launch_bounds__(256, 3) void conv_k(const u16* __restrict__ wmix,
                                                 const u16* __restrict__ xpadT,
                                                 float* __restrict__ out) {
    __shared__ u16 As[128 * 64];     // 16 KB
    __shared__ u16 Bs[256 * 72];     // 36 KB
    char* Asc = (char*)As;
    char* Bsc = (char*)Bs;

    int tid  = threadIdx.x;
    int lane = tid & 63, wid = tid >> 6;
    int ln = lane & 15, hi = lane >> 4;

    int bid = blockIdx.x;
    int b   = bid / 56;
    int rem = bid % 56;
    int mt  = rem / 28, nt = rem % 28;
    int obase = mt * 128;
    int h0 = nt * 2;          // image row base
    int p0 = nt * 112;

    const u16* wpanel = wmix + (size_t)b * 9 * 65536 + obase * 256;   // + kk*65536 + row*256 + c
    const u16* xbase  = xpadT + ((size_t)(b * HP + h0)) * WP * NC;    // + rw*256 + c

    // accumulators
    f32x4 acc[2][7];
    #pragma unroll
    for (int mi = 0; mi < 2; ++mi)
        #pragma unroll
        for (int ni = 0; ni < 7; ++ni) acc[mi][ni] = (f32x4){0.f, 0.f, 0.f, 0.f};

    // per-lane B fragment row bases: p = ni*16 + ln ; rw = base0 + (dh+1)*64 + dw
    int base144[7];
    #pragma unroll
    for (int ni = 0; ni < 7; ++ni) {
        int p  = ni * 16 + ln;
        int hr = (p >= 56) ? 1 : 0;
        int wv = p - hr * 56;
        base144[ni] = (hr * 64 + wv + 1) * 144;     // bytes
    }
    // A fragment byte offsets (row&7 == ln&7 since wid*32, mi*16 are mult of 8)
    int aoff[2][2];
    #pragma unroll
    for (int mi = 0; mi < 2; ++mi)
        #pragma unroll
        for (int ks = 0; ks < 2; ++ks)
            aoff[mi][ks] = (wid * 32 + mi * 16 + ln) * 128 + (((ks * 4 + hi) ^ (ln & 7)) << 4);

    // staging bases
    int gsA  = (tid & 7) ^ ((tid >> 3) & 7);              // pre-swizzled source slot
    int asrc = (tid >> 3) * 256 + gsA * 8;                // elements
    int bsrc = (tid >> 3) * 256 + (tid & 7) * 8;          // elements
    int bdst = (tid >> 3) * 144 + (tid & 7) * 16;         // bytes

    for (int c0 = 0; c0 < 256; c0 += 64) {
        __syncthreads();
        { // stage B (shared across all 9 taps)
            const u16* gp = xbase + c0 + bsrc;
            #pragma unroll
            for (int i = 0; i < 8; ++i) {
                u16x8 v = *(const u16x8*)(gp + i * 8192);
                *(u16x8*)(Bsc + bdst + i * 4608) = v;
            }
        }
        { // stage A kk=0
            const u16* gp = wpanel + c0 + asrc;
            #pragma unroll
            for (int i = 0; i < 4; ++i) {
                u16x8 v = *(const u16x8*)(gp + i * 8192);
                *(u16x8*)(Asc + tid * 16 + i * 4096) = v;
            }
        }
        __syncthreads();

        #pragma unroll
        for (int kk = 0; kk < 9; ++kk) {
            if (kk > 0) {
                __syncthreads();
                const u16* gp = wpanel + kk * 65536 + c0 + asrc;
                #pragma unroll
                for (int i = 0; i < 4; ++i) {
                    u16x8 v = *(const u16x8*)(gp + i * 8192);
                    *(u16x8*)(Asc + tid * 16 + i * 4096) = v;
                }
                __syncthreads();
            }
            int soff = ((kk / 3) * 64 + (kk % 3) - 1) * 144;    // ((dh+1)*64+dw)*144
            #pragma unroll
            for (int ks = 0; ks < 2; ++ks) {
                bf16x8 a0 = *(const bf16x8*)(Asc + aoff[0][ks]);
                bf16x8 a1 = *(const bf16x8*)(Asc + aoff[1][ks]);
                int kb = (ks * 4 + hi) * 16;
                #pragma unroll
                for (int ni = 0; ni < 7; ++ni) {
                    bf16x8 bv = *(const bf16x8*)(Bsc + base144[ni] + soff + kb);
                    acc[0][ni] = __builtin_amdgcn_mfma_f32_16x16x32_bf16(a0, bv, acc[0][ni], 0, 0, 0);
                    acc[1][ni] = __builtin_amdgcn_mfma_f32_16x16x32_bf16(a1, bv, acc[1][ni], 0, 0, 0);
                }
            }
        }
    }

    // epilogue: D col = lane&15 (p), row = (lane>>4)*4 + reg (o)
    float* op = out + ((size_t)(b * NO + obase + wid * 32)) * NP + p0;
    #pragma unroll
    for (int mi = 0; mi < 2; ++mi)
        #pragma unroll
        for (int ni = 0; ni < 7; ++ni) {
            f32x4 v = acc[mi][ni];
            int col = ni * 16 + ln;
            #pragma unroll
            for (int rg = 0; rg < 4; ++rg) {
                int row = mi * 16 + hi * 4 + rg;
                op[(size_t)row * NP + col] = v[rg];
            }
        }
}

// ---------------------------------------------------------------- launch
extern "C" void kernel_launch(void* const* d_in, const int* in_sizes, int n_in,
                              void* d_out, int out_size, void* d_ws, size_t ws_size,
                              hipStream_t stream) {
    (void)in_sizes; (void)n_in; (void)out_size; (void)ws_size;
    const float* x        = (const float*)d_in[0];
    const float* proj_w   = (const float*)d_in[1];
    const float* proj_b   = (const float*)d_in[2];
    const float* expert_w = (const float*)d_in[3];
    float* out = (float*)d_out;
    char*  ws  = (char*)d_ws;

    u16*   wmix   = (u16*)(ws + WMIX_OFF);
    u16*   xpadT  = (u16*)(ws + XPT_OFF);
    float* pooled = (float*)(ws + POOL_OFF);
    float* rbuf   = (float*)(ws + RBUF_OFF);

    zero_pooled<<<dim3(32), dim3(256), 0, stream>>>(pooled);
    prep_x<<<dim3(32 * 58), dim3(256), 0, stream>>>(x, xpadT, pooled);
    routing<<<dim3(32), dim3(64), 0, stream>>>(pooled, proj_w, proj_b, rbuf);
    mix_w<<<dim3(256), dim3(256), 0, stream>>>(expert_w, rbuf, wmix);
    conv_k<<<dim3(32 * 56), dim3(256), 0, stream>>>(wmix, xpadT, out);
}

// Round 2
// 204.583 us; speedup vs baseline: 1.5362x; 1.5362x over previous
//
#include <hip/hip_runtime.h>
#include <math.h>

typedef unsigned short u16;
typedef __attribute__((ext_vector_type(8))) short    bf16x8;
typedef __attribute__((ext_vector_type(8))) unsigned short u16x8;
typedef __attribute__((ext_vector_type(4))) float    f32x4;

// Problem constants
#define NB   32        // batch
#define NC   256       // in channels
#define NO   256       // out channels
#define NH   56
#define NW   56
#define NP   3136      // H*W
#define NE   8
#define NID  64
#define HP   58        // padded rows
#define WP   64        // padded row width (aligned)

// Workspace layout (bytes)
#define WMIX_OFF   0                    // u16 [32][9][256][256] = 37,748,736 B
#define XPT_OFF    37748736             // u16 [32][58][64][256] = 60,817,408 B
#define POOL_OFF   98566144             // f32 [32][256]
#define RBUF_OFF   98598912             // f32 [32][8]

__device__ __forceinline__ u16 f2bf(float f) {
    unsigned u = __float_as_uint(f);
    unsigned r = (u + 0x7FFFu + ((u >> 16) & 1u)) >> 16;   // RNE
    return (u16)r;
}

// ---------------------------------------------------------------- kernel 0
// Zero pooled accumulators + the two border rows (h'=0,57) of xpadT.
__global__ __launch_bounds__(256) void zero_k(float* __restrict__ pooled,
                                              u16* __restrict__ xpadT) {
    int b = blockIdx.x, t = threadIdx.x;
    pooled[b * 256 + t] = 0.0f;
    u16x8 z = {0, 0, 0, 0, 0, 0, 0, 0};
    u16* r0 = xpadT + ((size_t)(b * HP + 0)) * WP * NC;
    u16* r1 = xpadT + ((size_t)(b * HP + 57)) * WP * NC;
    #pragma unroll
    for (int i = 0; i < 8; ++i) {
        *(u16x8*)&r0[(i * 256 + t) * 8] = z;
        *(u16x8*)&r1[(i * 256 + t) * 8] = z;
    }
}

// ---------------------------------------------------------------- kernel 1
// One block per (b,h): NCHW fp32 -> padded NHWC bf16 row transpose + pooling
// partial sums (computed from the LDS tile; no shuffles).
// LDS tile: u16 [64 w][32 slots of 8c], physical slot = s ^ (w>>2).
__global__ __launch_bounds__(256) void transpose_pool_k(const float* __restrict__ x,
                                                        u16* __restrict__ xpadT,
                                                        float* __restrict__ pooled) {
    __shared__ u16 tile[64 * 256];          // 32 KB
    int b = blockIdx.x / 56;
    int h = blockIdx.x % 56;
    int t = threadIdx.x;

    // ---- write phase: coalesced float4 reads along w
    int w4 = t & 15, c_sub = t >> 4;        // w4: 0..13 valid (56 w), c_sub: 0..15
    if (w4 < 14) {
        const float* xp = x + ((size_t)b * NC + c_sub) * NP + (size_t)h * NW + w4 * 4;
        #pragma unroll
        for (int it = 0; it < 16; ++it) {
            int c = it * 16 + c_sub;
            f32x4 v = *(const f32x4*)(xp + (size_t)it * 16 * NP);
            int key = w4;                    // (w>>2) for all 4 written rows
            int base = ((c >> 3) ^ key) * 8 + (c & 7);
            #pragma unroll
            for (int i = 0; i < 4; ++i)
                tile[(w4 * 4 + i) * 256 + base] = f2bf(v[i]);
        }
    }
    __syncthreads();

    // ---- global write phase: u16x8 along c, 1 KB/wave
    {
        int c8 = t & 31, whi = t >> 5;       // whi: 0..7
        u16* orow = xpadT + ((size_t)(b * HP + h + 1)) * WP * NC;
        #pragma unroll
        for (int j = 0; j < 8; ++j) {
            int wp = whi * 8 + j;
            u16x8 v = {0, 0, 0, 0, 0, 0, 0, 0};
            if (wp >= 1 && wp <= 56) {
                int w = wp - 1;
                v = *(const u16x8*)&tile[w * 256 + ((c8 ^ (w >> 2)) * 8)];
            }
            *(u16x8*)&orow[wp * NC + c8 * 8] = v;
        }
    }

    // ---- pool phase: per-thread channel sum over the 56 w of this row
    {
        int c = t;
        int s = c >> 3, sub = c & 7;
        float sum = 0.0f;
        #pragma unroll
        for (int w = 0; w < 56; ++w) {
            u16 u = tile[w * 256 + ((s ^ (w >> 2)) * 8) + sub];
            sum += __uint_as_float(((unsigned)u) << 16);
        }
        atomicAdd(&pooled[b * 256 + c], sum);
    }
}

// ---------------------------------------------------------------- kernel 2
// routing: rt = (pooled/3136) @ proj_w^T + proj_b ; sigmoid ; avgpool(8) -> r[32][8]
__global__ __launch_bounds__(64) void routing(const float* __restrict__ pooled,
                                              const float* __restrict__ proj_w,
                                              const float* __restrict__ proj_b,
                                              float* __restrict__ r) {
    __shared__ float ps[256];
    __shared__ float sg[64];
    int b = blockIdx.x, j = threadIdx.x;
    for (int i = j; i < 256; i += 64) ps[i] = pooled[b * NC + i] * (1.0f / 3136.0f);
    __syncthreads();
    float acc = proj_b[j];
    for (int c = 0; c < 256; ++c) acc += ps[c] * proj_w[j * NC + c];
    sg[j] = 1.0f / (1.0f + expf(-acc));
    __syncthreads();
    if (j < NE) {
        float s = 0.0f;
        #pragma unroll
        for (int q = 0; q < 8; ++q) s += sg[j * 8 + q];
        r[b * NE + j] = s * 0.125f;
    }
}

// ---------------------------------------------------------------- kernel 3
// wmix[b][kk][o][c] = bf16( sum_e r[b][e] * expert_w[e][o][c][kk] )
__global__ __launch_bounds__(256) void mix_w(const float* __restrict__ expert_w,
                                             const float* __restrict__ r,
                                             u16* __restrict__ wmix) {
    __shared__ float lr[256];
    int o = blockIdx.x, c = threadIdx.x;
    lr[c] = r[c];                               // 32*8 = 256
    __syncthreads();
    float w[8][9];
    #pragma unroll
    for (int e = 0; e < 8; ++e) {
        const float* p = expert_w + ((size_t)((e * NO + o) * NC + c)) * 9;
        #pragma unroll
        for (int kk = 0; kk < 9; ++kk) w[e][kk] = p[kk];
    }
    for (int b = 0; b < NB; ++b) {
        float acc[9] = {0, 0, 0, 0, 0, 0, 0, 0, 0};
        #pragma unroll
        for (int e = 0; e < 8; ++e) {
            float rv = lr[b * 8 + e];
            #pragma unroll
            for (int kk = 0; kk < 9; ++kk) acc[kk] += rv * w[e][kk];
        }
        #pragma unroll
        for (int kk = 0; kk < 9; ++kk)
            wmix[((size_t)((b * 9 + kk) * NO + o)) * NC + c] = f2bf(acc[kk]);
    }
}

// ---------------------------------------------------------------- kernel 4
// Implicit-GEMM conv: per block b, o-tile 128, p-tile 112 (2 image rows).
// out[o][p] = sum_{kk,c} wmix[b][kk][o][c] * xpadT[b][h+dh+1][w+dw+1][c]
// A LDS: [128 o][64 c] bf16, XOR-swizzled 16B slots (slot g holds col g^(row&7)).
// B LDS: [256 rw][72 c] bf16 padded (rw = (r)*64 + w', 4 padded image rows).
__global__ __launch_bounds__(256, 3) void conv_k(const u16* __restrict__ wmix,
                                                 const u16* __restrict__ xpadT,
                                                 float* __restrict__ out) {
    __shared__ u16 As[128 * 64];     // 16 KB
    __shared__ u16 Bs[256 * 72];     // 36 KB
    char* Asc = (char*)As;
    char* Bsc = (char*)Bs;

    int tid  = threadIdx.x;
    int lane = tid & 63, wid = tid >> 6;
    int ln = lane & 15, hi = lane >> 4;

    int bid = blockIdx.x;
    int b   = bid / 56;
    int rem = bid % 56;
    int mt  = rem / 28, nt = rem % 28;
    int obase = mt * 128;
    int h0 = nt * 2;          // image row base
    int p0 = nt * 112;

    const u16* wpanel = wmix + (size_t)b * 9 * 65536 + obase * 256;   // + kk*65536 + row*256 + c
    const u16* xbase  = xpadT + ((size_t)(b * HP + h0)) * WP * NC;    // + rw*256 + c

    // accumulators
    f32x4 acc[2][7];
    #pragma unroll
    for (int mi = 0; mi < 2; ++mi)
        #pragma unroll
        for (int ni = 0; ni < 7; ++ni) acc[mi][ni] = (f32x4){0.f, 0.f, 0.f, 0.f};

    // per-lane B fragment row bases: p = ni*16 + ln ; rw = base0 + (dh+1)*64 + dw
    int base144[7];
    #pragma unroll
    for (int ni = 0; ni < 7; ++ni) {
        int p  = ni * 16 + ln;
        int hr = (p >= 56) ? 1 : 0;
        int wv = p - hr * 56;
        base144[ni] = (hr * 64 + wv + 1) * 144;     // bytes
    }
    // A fragment byte offsets (row&7 == ln&7 since wid*32, mi*16 are mult of 8)
    int aoff[2][2];
    #pragma unroll
    for (int mi = 0; mi < 2; ++mi)
        #pragma unroll
        for (int ks = 0; ks < 2; ++ks)
            aoff[mi][ks] = (wid * 32 + mi * 16 + ln) * 128 + (((ks * 4 + hi) ^ (ln & 7)) << 4);

    // staging bases
    int gsA  = (tid & 7) ^ ((tid >> 3) & 7);              // pre-swizzled source slot
    int asrc = (tid >> 3) * 256 + gsA * 8;                // elements
    int bsrc = (tid >> 3) * 256 + (tid & 7) * 8;          // elements
    int bdst = (tid >> 3) * 144 + (tid & 7) * 16;         // bytes

    for (int c0 = 0; c0 < 256; c0 += 64) {
        __syncthreads();
        { // stage B (shared across all 9 taps)
            const u16* gp = xbase + c0 + bsrc;
            #pragma unroll
            for (int i = 0; i < 8; ++i) {
                u16x8 v = *(const u16x8*)(gp + i * 8192);
                *(u16x8*)(Bsc + bdst + i * 4608) = v;
            }
        }
        { // stage A kk=0
            const u16* gp = wpanel + c0 + asrc;
            #pragma unroll
            for (int i = 0; i < 4; ++i) {
                u16x8 v = *(const u16x8*)(gp + i * 8192);
                *(u16x8*)(Asc + tid * 16 + i * 4096) = v;
            }
        }
        __syncthreads();

        #pragma unroll
        for (int kk = 0; kk < 9; ++kk) {
            if (kk > 0) {
                __syncthreads();
                const u16* gp = wpanel + kk * 65536 + c0 + asrc;
                #pragma unroll
                for (int i = 0; i < 4; ++i) {
                    u16x8 v = *(const u16x8*)(gp + i * 8192);
                    *(u16x8*)(Asc + tid * 16 + i * 4096) = v;
                }
                __syncthreads();
            }
            int soff = ((kk / 3) * 64 + (kk % 3) - 1) * 144;    // ((dh+1)*64+dw)*144
            #pragma unroll
            for (int ks = 0; ks < 2; ++ks) {
                bf16x8 a0 = *(const bf16x8*)(Asc + aoff[0][ks]);
                bf16x8 a1 = *(const bf16x8*)(Asc + aoff[1][ks]);
                int kb = (ks * 4 + hi) * 16;
                #pragma unroll
                for (int ni = 0; ni < 7; ++ni) {
                    bf16x8 bv = *(const bf16x8*)(Bsc + base144[ni] + soff + kb);
                    acc[0][ni] = __builtin_amdgcn_mfma_f32_16x16x32_bf16(a0, bv, acc[0][ni], 0, 0, 0);
                    acc[1][ni] = __builtin_amdgcn_mfma_f32_16x16x32_bf16(a1, bv, acc[1][ni], 0, 0, 0);
                }
            }
        }
    }

    // epilogue: D col = lane&15 (p), row = (lane>>4)*4 + reg (o)
    float* op = out + ((size_t)(b * NO + obase + wid * 32)) * NP + p0;
    #pragma unroll
    for (int mi = 0; mi < 2; ++mi)
        #pragma unroll
        for (int ni = 0; ni < 7; ++ni) {
            f32x4 v = acc[mi][ni];
            int col = ni * 16 + ln;
            #pragma unroll
            for (int rg = 0; rg < 4; ++rg) {
                int row = mi * 16 + hi * 4 + rg;
                op[(size_t)row * NP + col] = v[rg];
            }
        }
}

// ---------------------------------------------------------------- launch
extern "C" void kernel_launch(void* const* d_in, const int* in_sizes, int n_in,
                              void* d_out, int out_size, void* d_ws, size_t ws_size,
                              hipStream_t stream) {
    (void)in_sizes; (void)n_in; (void)out_size; (void)ws_size;
    const float* x        = (const float*)d_in[0];
    const float* proj_w   = (const float*)d_in[1];
    const float* proj_b   = (const float*)d_in[2];
    const float* expert_w = (const float*)d_in[3];
    float* out = (float*)d_out;
    char*  ws  = (char*)d_ws;

    u16*   wmix   = (u16*)(ws + WMIX_OFF);
    u16*   xpadT  = (u16*)(ws + XPT_OFF);
    float* pooled = (float*)(ws + POOL_OFF);
    float* rbuf   = (float*)(ws + RBUF_OFF);

    zero_k<<<dim3(32), dim3(256), 0, stream>>>(pooled, xpadT);
    transpose_pool_k<<<dim3(32 * 56), dim3(256), 0, stream>>>(x, xpadT, pooled);
    routing<<<dim3(32), dim3(64), 0, stream>>>(pooled, proj_w, proj_b, rbuf);
    mix_w<<<dim3(256), dim3(256), 0, stream>>>(expert_w, rbuf, wmix);
    conv_k<<<dim3(32 * 56), dim3(256), 0, stream>>>(wmix, xpadT, out);
}